// Round 3
// baseline (60426.184 us; speedup 1.0000x reference)
//
#include <hip/hip_runtime.h>
#include <hip/hip_fp16.h>

// WaveNet forward, MI355X. Round 3: fp32 I/O (per reference dtypes).
// B=4, T=32768, NM=80, RC=120, SC=240, NB=16, ND=8, NC=256.
// Weights read fp32 directly from d_in (scalar loads); res ping-pong fp16 in
// d_ws (63 MB); skip accumulator fp32 in d_out rows 0..239; final output fp32
// written in place (each (b,t0) tile stages skip in LDS before overwriting).

#define BSZ  4
#define TLEN 32768
#define NMEL 80
#define RCH  120
#define SCH  240
#define NBLK 16
#define NCLS 256
#define TS   64   // t-columns per workgroup

__device__ __forceinline__ float h2f(unsigned short u) {
    return __half2float(__ushort_as_half(u));
}
__device__ __forceinline__ unsigned short f2h(float f) {
    return __half_as_ushort(__float2half(f));
}

// ---- init: res0[b,c,t] = wav_w[c]*wav[b,t] + wav_b[c], fp16 ----------------
__global__ void k_init(const float* __restrict__ wav,
                       const float* __restrict__ wav_w,
                       const float* __restrict__ wav_b,
                       unsigned short* __restrict__ res) {
    int idx = blockIdx.x * 256 + threadIdx.x;          // exact multiple of total
    int t = idx % TLEN;
    int c = (idx / TLEN) % RCH;
    int b = idx / (TLEN * RCH);
    res[idx] = f2h(wav_w[c] * wav[b * TLEN + t] + wav_b[c]);
}

// ---- one residual block ----------------------------------------------------
// g = Wd0 @ res[t-d] + Wd1 @ res[t] + Wc @ cond + bd + bc    (240 rows)
// out = tanh(g[0:120]) * sigmoid(g[120:240])
// skip += Ws @ out + bs ; resOut = Wr @ out + br + resIn
__global__ __launch_bounds__(256) void k_block(
    const unsigned short* __restrict__ resIn,  // fp16 [B][RC][T]
    unsigned short* __restrict__ resOut,       // fp16 [B][RC][T]
    float* __restrict__ skip,                  // fp32 [B][256][T] rows 0..239
    const float* __restrict__ cond,            // fp32 [B][NM][T]
    const float* __restrict__ wd,   // [240][120][2]
    const float* __restrict__ bd,   // [240]
    const float* __restrict__ wc,   // [240][80]
    const float* __restrict__ bc,   // [240]
    const float* __restrict__ wsk,  // [240][120]
    const float* __restrict__ bsk,  // [240]
    const float* __restrict__ wr,   // [120][120]
    const float* __restrict__ br,   // [120]
    int d) {
    __shared__ unsigned short X[(2 * RCH + NMEL) * TS];  // fp16: res[t-d], res[t], cond
    __shared__ unsigned short O[RCH * TS];               // fp16 gated activation

    const int tid = threadIdx.x;
    const int t0  = blockIdx.x * TS;
    const int b   = blockIdx.y;

    const unsigned short* resb = resIn + (size_t)b * RCH * TLEN;
    for (int idx = tid; idx < RCH * TS; idx += 256) {    // shifted res
        int k = idx / TS, tt = idx % TS;
        int tc = t0 + tt - d;
        X[idx] = tc >= 0 ? resb[(size_t)k * TLEN + tc] : (unsigned short)0;
    }
    for (int idx = tid; idx < RCH * TS; idx += 256) {    // current res
        int k = idx / TS, tt = idx % TS;
        X[RCH * TS + idx] = resb[(size_t)k * TLEN + t0 + tt];
    }
    for (int idx = tid; idx < NMEL * TS; idx += 256) {   // cond
        int k = idx / TS, tt = idx % TS;
        X[2 * RCH * TS + idx] = f2h(cond[((size_t)b * NMEL + k) * TLEN + t0 + tt]);
    }
    __syncthreads();

    const int t  = tid & (TS - 1);
    const int og = __builtin_amdgcn_readfirstlane(tid >> 6);  // 0..3, wave-uniform
    const int o0 = og * 30;

    float gt[30], gs[30];
#pragma unroll
    for (int j = 0; j < 30; j++) {
        gt[j] = bd[o0 + j] + bc[o0 + j];
        gs[j] = bd[o0 + j + 120] + bc[o0 + j + 120];
    }
    for (int k = 0; k < RCH; k++) {
        float xs = h2f(X[k * TS + t]);
        float xc = h2f(X[(RCH + k) * TS + t]);
#pragma unroll
        for (int j = 0; j < 30; j++) {
            const float* w0 = wd + ((o0 + j) * RCH + k) * 2;
            const float* w1 = wd + ((o0 + j + 120) * RCH + k) * 2;
            gt[j] += w0[0] * xs + w0[1] * xc;
            gs[j] += w1[0] * xs + w1[1] * xc;
        }
    }
    for (int k = 0; k < NMEL; k++) {
        float cv = h2f(X[(2 * RCH + k) * TS + t]);
#pragma unroll
        for (int j = 0; j < 30; j++) {
            gt[j] += wc[(o0 + j) * NMEL + k] * cv;
            gs[j] += wc[(o0 + j + 120) * NMEL + k] * cv;
        }
    }
#pragma unroll
    for (int j = 0; j < 30; j++) {
        float v = tanhf(gt[j]) * (1.f / (1.f + __expf(-gs[j])));
        O[(o0 + j) * TS + t] = f2h(v);
    }
    __syncthreads();

    // skip GEMM: 240 rows, 60 per wave, fp32 accumulate into d_out
    {
        const int s0 = og * 60;
        float a[60];
#pragma unroll
        for (int j = 0; j < 60; j++) a[j] = bsk[s0 + j];
        for (int k = 0; k < RCH; k++) {
            float ov = h2f(O[k * TS + t]);
#pragma unroll
            for (int j = 0; j < 60; j++) a[j] += wsk[(s0 + j) * RCH + k] * ov;
        }
        float* skb = skip + ((size_t)b * NCLS + s0) * TLEN + t0 + t;
#pragma unroll
        for (int j = 0; j < 60; j++) {
            size_t off = (size_t)j * TLEN;
            skb[off] += a[j];
        }
    }
    // res GEMM: 120 rows, 30 per wave, + residual (res[t] reused from LDS)
    {
        const int r0 = og * 30;
        float a[30];
#pragma unroll
        for (int j = 0; j < 30; j++) a[j] = br[r0 + j];
        for (int k = 0; k < RCH; k++) {
            float ov = h2f(O[k * TS + t]);
#pragma unroll
            for (int j = 0; j < 30; j++) a[j] += wr[(r0 + j) * RCH + k] * ov;
        }
        unsigned short* rout = resOut + (size_t)b * RCH * TLEN + t0 + t;
#pragma unroll
        for (int j = 0; j < 30; j++)
            rout[(size_t)(r0 + j) * TLEN] =
                f2h(a[j] + h2f(X[(RCH + r0 + j) * TS + t]));
    }
}

// ---- final: end = We @ relu(Wo @ relu(skip) + bo) + be ---------------------
// skip fp32 in d_out rows 0..239; output fp32 written to the same (b,t0) tile
// after skip is staged in LDS — each tile owned by exactly one workgroup.
__global__ __launch_bounds__(256) void k_final(
    const float* __restrict__ wo, const float* __restrict__ bo,
    const float* __restrict__ we, const float* __restrict__ be,
    float* __restrict__ io) {   // in: fp32 skip (rows<240), out: fp32 end
    __shared__ unsigned short S[SCH * TS];
    __shared__ unsigned short E[NCLS * TS];
    const int tid = threadIdx.x;
    const int t0  = blockIdx.x * TS;
    const int b   = blockIdx.y;

    for (int idx = tid; idx < SCH * TS; idx += 256) {
        int k = idx / TS, tt = idx % TS;
        float v = io[((size_t)b * NCLS + k) * TLEN + t0 + tt];
        S[idx] = f2h(fmaxf(v, 0.f));
    }
    __syncthreads();

    const int t  = tid & (TS - 1);
    const int og = __builtin_amdgcn_readfirstlane(tid >> 6);
    const int ob = og * 64;
    {
        float a[64];
#pragma unroll
        for (int j = 0; j < 64; j++) a[j] = bo[ob + j];
        for (int k = 0; k < SCH; k++) {
            float sv = h2f(S[k * TS + t]);
#pragma unroll
            for (int j = 0; j < 64; j++) a[j] += wo[(ob + j) * SCH + k] * sv;
        }
#pragma unroll
        for (int j = 0; j < 64; j++) E[(ob + j) * TS + t] = f2h(fmaxf(a[j], 0.f));
    }
    __syncthreads();
    {
        float a[64];
#pragma unroll
        for (int j = 0; j < 64; j++) a[j] = be[ob + j];
        for (int k = 0; k < NCLS; k++) {
            float ev = h2f(E[k * TS + t]);
#pragma unroll
            for (int j = 0; j < 64; j++) a[j] += we[(ob + j) * NCLS + k] * ev;
        }
#pragma unroll
        for (int j = 0; j < 64; j++)
            io[((size_t)b * NCLS + ob + j) * TLEN + t0 + t] = a[j];
    }
}

extern "C" void kernel_launch(void* const* d_in, const int* in_sizes, int n_in,
                              void* d_out, int out_size, void* d_ws, size_t ws_size,
                              hipStream_t stream) {
    (void)in_sizes; (void)n_in; (void)ws_size;
    const float* wav    = (const float*)d_in[0];
    const float* cond   = (const float*)d_in[1];
    const float* wav_w  = (const float*)d_in[2];
    const float* wav_b  = (const float*)d_in[3];
    const float* cond_w = (const float*)d_in[4];
    const float* cond_b = (const float*)d_in[5];
    const float* dil_w  = (const float*)d_in[6];
    const float* dil_b  = (const float*)d_in[7];
    const float* skip_w = (const float*)d_in[8];
    const float* skip_b = (const float*)d_in[9];
    const float* res_w  = (const float*)d_in[10];
    const float* res_b  = (const float*)d_in[11];
    const float* out_w  = (const float*)d_in[12];
    const float* out_b  = (const float*)d_in[13];
    const float* end_w  = (const float*)d_in[14];
    const float* end_b  = (const float*)d_in[15];

    const size_t resN = (size_t)BSZ * RCH * TLEN;    // 15,728,640 elements
    unsigned short* resA = (unsigned short*)d_ws;    // fp16, 31.5 MB
    unsigned short* resB = resA + resN;              // fp16, 31.5 MB (63 MB total)
    float* skip = (float*)d_out;                     // fp32 [B][256][T]

    hipMemsetAsync(skip, 0, (size_t)out_size * sizeof(float), stream);
    k_init<<<dim3((unsigned)(resN / 256)), 256, 0, stream>>>(wav, wav_w, wav_b, resA);

    unsigned short* rin = resA;
    unsigned short* rout = resB;
    for (int i = 0; i < NBLK; i++) {
        int d = 1 << (i & 7);
        k_block<<<dim3(TLEN / TS, BSZ), 256, 0, stream>>>(
            rin, rout, skip, cond,
            dil_w  + (size_t)i * 2 * RCH * RCH * 2,
            dil_b  + (size_t)i * 2 * RCH,
            cond_w + (size_t)i * 2 * RCH * NMEL,
            cond_b + (size_t)i * 2 * RCH,
            skip_w + (size_t)i * SCH * RCH,
            skip_b + (size_t)i * SCH,
            res_w  + (size_t)i * RCH * RCH,
            res_b  + (size_t)i * RCH,
            d);
        unsigned short* tmp = rin; rin = rout; rout = tmp;
    }
    k_final<<<dim3(TLEN / TS, BSZ), 256, 0, stream>>>(
        out_w, out_b, end_w, end_b, skip);
}

// Round 4
// 2158.646 us; speedup vs baseline: 27.9926x; 27.9926x over previous
//
#include <hip/hip_runtime.h>

// WaveNet forward, MI355X — round 4: bf16 MFMA (16x16x32) rewrite.
// B=4, T=32768, NM=80, RC=120, SC=240, NB=16, ND=8, NC=256. fp32 I/O.
//
// Layout decisions (all verified-by-construction against guide §3 layouts):
//  - A-frag: lane holds A[m=lane&15][k=(lane>>4)*8+j]  (8 bf16 = dwordx4)
//  - B-frag: lane holds B[n=lane&15][k=(lane>>4)*8+j]
//  - C/D   : reg r -> row=(lane>>4)*4+r, col=lane&15
//  - res/cond stored CHANNEL-LAST bf16 ([B][T][128] / [B][T][96]) so B-frags
//    are single coalesced dwordx4 loads (k = channel is contiguous).
//  - Weights prepacked to A-frag-linear order in ws; gate rows interleaved
//    (tanh_c, sig_c) so one lane's C-quad = both branches of 2 channels.
//  - skip accumulates fp32 in d_out rows 0..239 (proven safe in round 3).

#define BSZ  4
#define TLEN 32768
#define NMEL 80
#define RCH  120
#define SCH  240
#define NBLK 16
#define NCLS 256
#define CP   128   // res channel pad (channels 120..127 always zero)
#define CC   96    // cond channel pad (channels 80..95 zero)
#define TSB  128   // t-cols per k_block wg
#define TSF  64    // t-cols per k_final wg
#define OUTS 136   // LDS col stride for out tile (2-way-conflict-free)
#define XES  264   // LDS col stride in k_final

typedef __attribute__((ext_vector_type(8))) short short8;
typedef __attribute__((ext_vector_type(4))) float floatx4;
#define MFMA16 __builtin_amdgcn_mfma_f32_16x16x32_bf16

__device__ __forceinline__ float bf2f(unsigned short u) {
    return __uint_as_float(((unsigned)u) << 16);
}
__device__ __forceinline__ unsigned short f2bf(float f) {
    unsigned x = __float_as_uint(f);
    return (unsigned short)((x + 0x7fffu + ((x >> 16) & 1u)) >> 16);  // rne
}
__device__ __forceinline__ float tanh_ap(float x) {
    x = fminf(fmaxf(x, -18.f), 18.f);
    float e = __expf(2.f * x);
    return (e - 1.f) / (e + 1.f);
}
__device__ __forceinline__ float sigm_ap(float x) {
    x = fminf(fmaxf(x, -30.f), 30.f);
    return 1.f / (1.f + __expf(-x));
}

// ---- packed-weight geometry ------------------------------------------------
// frags per block: gate 15mt*11ks=165 | skip 15*4=60 | res 8*4=32  => 257
// finals: out 16*8=128 | end 16*8=128. total frags 16*257+256 = 4368.
// frag elem layout: [fid][lane][j] (512 bf16/frag) -> lane's 8 elems contiguous.
#define FR_BLK   257
#define FR_TOT   4368
#define NWELEM   (FR_TOT * 512)          // 2,236,416
#define BIA_BLK  608                     // gate 240 | skip 240 | res 128
#define NBELEM   (NBLK * BIA_BLK + 512)  // 10,240

__global__ void k_packw(const float* __restrict__ dil_w, const float* __restrict__ cond_w,
                        const float* __restrict__ skip_w, const float* __restrict__ res_w,
                        const float* __restrict__ out_w,  const float* __restrict__ end_w,
                        unsigned short* __restrict__ dst) {
    int idx = blockIdx.x * 256 + threadIdx.x;
    if (idx >= NWELEM) return;
    int fid = idx >> 9;
    int r   = idx & 511;
    int lane = r >> 3, j = r & 7;
    int m16 = lane & 15, q = lane >> 4;
    float v = 0.f;
    if (fid < NBLK * FR_BLK) {
        int blk = fid / FR_BLK, f = fid % FR_BLK;
        if (f < 165) {                      // gate: [240 interleaved][352]
            int mt = f / 11, ks = f % 11;
            int row = 16 * mt + m16;        // packed row: even=tanh, odd=sig
            int kk  = ks * 32 + q * 8 + j;
            int c = row >> 1, br = row & 1;
            int srow = c + 120 * br;        // source row in [240]
            if (kk < 128) {                 // seg: res[t-d] -> dil tap 0
                if (kk < 120) v = dil_w[((size_t)(blk * 240 + srow) * 120 + kk) * 2 + 0];
            } else if (kk < 256) {          // seg: res[t] -> dil tap 1
                int ch = kk - 128;
                if (ch < 120) v = dil_w[((size_t)(blk * 240 + srow) * 120 + ch) * 2 + 1];
            } else {                        // seg: cond
                int ch = kk - 256;
                if (ch < 80) v = cond_w[(size_t)(blk * 240 + srow) * 80 + ch];
            }
        } else if (f < 225) {               // skip: [240][128]
            int f2 = f - 165, mt = f2 / 4, ks = f2 % 4;
            int row = 16 * mt + m16;
            int kk = ks * 32 + q * 8 + j;
            if (kk < 120) v = skip_w[(size_t)(blk * 240 + row) * 120 + kk];
        } else {                            // res: [128][128]
            int f2 = f - 225, mt = f2 / 4, ks = f2 % 4;
            int row = 16 * mt + m16;
            int kk = ks * 32 + q * 8 + j;
            if (row < 120 && kk < 120) v = res_w[(size_t)(blk * 120 + row) * 120 + kk];
        }
    } else if (fid < NBLK * FR_BLK + 128) { // out_w: [256][256]
        int f = fid - NBLK * FR_BLK, mt = f / 8, ks = f % 8;
        int row = 16 * mt + m16;
        int kk = ks * 32 + q * 8 + j;
        if (kk < 240) v = out_w[(size_t)row * 240 + kk];
    } else {                                // end_w: [256][256]
        int f = fid - NBLK * FR_BLK - 128, mt = f / 8, ks = f % 8;
        int row = 16 * mt + m16;
        int kk = ks * 32 + q * 8 + j;
        v = end_w[(size_t)row * 256 + kk];
    }
    dst[idx] = f2bf(v);
}

__global__ void k_packb(const float* __restrict__ dil_b, const float* __restrict__ cond_b,
                        const float* __restrict__ skip_b, const float* __restrict__ res_b,
                        const float* __restrict__ out_b,  const float* __restrict__ end_b,
                        float* __restrict__ dst) {
    int idx = blockIdx.x * 256 + threadIdx.x;
    if (idx >= NBELEM) return;
    float v;
    if (idx < NBLK * BIA_BLK) {
        int blk = idx / BIA_BLK, f = idx % BIA_BLK;
        if (f < 240) {                      // gate packed (interleaved)
            int c = f >> 1, br = f & 1;
            int srow = c + 120 * br;
            v = dil_b[blk * 240 + srow] + cond_b[blk * 240 + srow];
        } else if (f < 480) {
            v = skip_b[blk * 240 + (f - 240)];
        } else {
            int rr = f - 480;
            v = rr < 120 ? res_b[blk * 120 + rr] : 0.f;
        }
    } else {
        int f = idx - NBLK * BIA_BLK;
        v = f < 256 ? out_b[f] : end_b[f - 256];
    }
    dst[idx] = v;
}

// res0[b][t][c] = wav_w[c]*wav[b][t] + wav_b[c], channel-last bf16, pad zeroed
__global__ void k_init2(const float* __restrict__ wav, const float* __restrict__ wav_w,
                        const float* __restrict__ wav_b, unsigned short* __restrict__ res) {
    int idx = blockIdx.x * 256 + threadIdx.x;   // B*T threads exactly
    float wv = wav[idx];
    unsigned* dst = (unsigned*)(res + (size_t)idx * CP);
#pragma unroll
    for (int c = 0; c < RCH; c += 2) {
        float v0 = wav_w[c] * wv + wav_b[c];
        float v1 = wav_w[c + 1] * wv + wav_b[c + 1];
        dst[c >> 1] = (unsigned)f2bf(v0) | ((unsigned)f2bf(v1) << 16);
    }
#pragma unroll
    for (int c = RCH; c < CP; c += 2) dst[c >> 1] = 0u;
}

// cond -> channel-last bf16 [B][T][96] via LDS transpose
__global__ __launch_bounds__(256) void k_packc(const float* __restrict__ cond,
                                               unsigned short* __restrict__ dst) {
    __shared__ unsigned short CT[64 * CC];
    const int tid = threadIdx.x;
    const int t0 = blockIdx.x * 64;
    const int b = blockIdx.y;
    for (int i = tid; i < NMEL * 64; i += 256) {
        int c = i >> 6, tt = i & 63;
        CT[tt * CC + c] = f2bf(cond[((size_t)b * NMEL + c) * TLEN + t0 + tt]);
    }
    for (int i = tid; i < (CC - NMEL) * 64; i += 256) {
        int c = NMEL + (i >> 6), tt = i & 63;
        CT[tt * CC + c] = 0;
    }
    __syncthreads();
    unsigned* dp = (unsigned*)(dst + ((size_t)b * TLEN + t0) * CC);
    const unsigned* sp = (const unsigned*)CT;
    for (int i = tid; i < 64 * (CC / 2); i += 256) dp[i] = sp[i];
}

// ---- residual block (MFMA) -------------------------------------------------
__global__ __launch_bounds__(256, 2) void k_block4(
    const unsigned short* __restrict__ resIn,   // bf16 [B][T][CP]
    unsigned short* __restrict__ resOut,        // bf16 [B][T][CP]
    const unsigned short* __restrict__ condp,   // bf16 [B][T][CC]
    float* __restrict__ skip,                   // fp32 [B][256][T] rows 0..239
    const unsigned short* __restrict__ wp,      // this block's packed frags
    const float* __restrict__ bp,               // this block's packed biases (608)
    int d) {
    __shared__ __align__(16) unsigned short OUT[TSB * OUTS];
    __shared__ __align__(16) float BIAS[BIA_BLK];

    const int tid = threadIdx.x;
    const int lane = tid & 63;
    const int n = lane & 15, q = lane >> 4;
    const int w = __builtin_amdgcn_readfirstlane(tid >> 6);  // wave 0..3
    const int t0 = blockIdx.x * TSB;
    const int b = blockIdx.y;
    const size_t bT = (size_t)b * TLEN;

    for (int i = tid; i < BIA_BLK; i += 256) BIAS[i] = bp[i];
    // zero out-tile pad channels 120..127 (read by skip/res GEMM K-pad)
    for (int i = tid; i < TSB * 8; i += 256) {
        int col = i >> 3, ch = RCH + (i & 7);
        OUT[col * OUTS + ch] = 0;
    }

    const int mtb = w * 4;
    const int mtn = (w == 3) ? 3 : 4;      // gate/skip m-tiles per wave
    const unsigned short* resb = resIn + bT * CP;
    const unsigned short* conb = condp + bT * CC;

    // ---------- gate GEMM: M=240(interleaved), K=352 ----------
    floatx4 acc[4][8];
#pragma unroll
    for (int mi = 0; mi < 4; mi++)
#pragma unroll
        for (int nt = 0; nt < 8; nt++) acc[mi][nt] = (floatx4){0.f, 0.f, 0.f, 0.f};

    for (int ks = 0; ks < 11; ks++) {
        short8 Bf[8];
        if (ks < 8) {
            const int dd = (ks < 4) ? d : 0;
            const int kl = (ks & 3) * 32 + q * 8;
            if (t0 >= TSB || dd == 0) {
#pragma unroll
                for (int nt = 0; nt < 8; nt++) {
                    int t = t0 + nt * 16 + n - dd;
                    Bf[nt] = *(const short8*)(resb + (size_t)t * CP + kl);
                }
            } else {  // first tile: mask t<0 (causal zero-pad)
#pragma unroll
                for (int nt = 0; nt < 8; nt++) {
                    int t = t0 + nt * 16 + n - dd;
                    int tc = t < 0 ? 0 : t;
                    short8 v = *(const short8*)(resb + (size_t)tc * CP + kl);
                    if (t < 0) v = (short8){0, 0, 0, 0, 0, 0, 0, 0};
                    Bf[nt] = v;
                }
            }
        } else {
            const int kl = (ks - 8) * 32 + q * 8;
#pragma unroll
            for (int nt = 0; nt < 8; nt++) {
                int t = t0 + nt * 16 + n;
                Bf[nt] = *(const short8*)(conb + (size_t)t * CC + kl);
            }
        }
#pragma unroll
        for (int mi = 0; mi < 4; mi++) {
            if (mi < mtn) {
                short8 A = *(const short8*)(wp + ((size_t)((mtb + mi) * 11 + ks) * 64 + lane) * 8);
#pragma unroll
                for (int nt = 0; nt < 8; nt++)
                    acc[mi][nt] = MFMA16(A, Bf[nt], acc[mi][nt], 0, 0, 0);
            }
        }
    }

    // gating epilogue -> OUT (bf16, [col][ch])
#pragma unroll
    for (int mi = 0; mi < 4; mi++) {
        if (mi < mtn) {
            int mt = mtb + mi;
            int p0 = 16 * mt + 4 * q;     // packed rows p0..p0+3 (t,s,t,s)
            int ch = 8 * mt + 2 * q;      // out channels ch, ch+1
            float bt0 = BIAS[p0], bs0 = BIAS[p0 + 1];
            float bt1 = BIAS[p0 + 2], bs1 = BIAS[p0 + 3];
#pragma unroll
            for (int nt = 0; nt < 8; nt++) {
                int col = nt * 16 + n;
                float o0 = tanh_ap(acc[mi][nt][0] + bt0) * sigm_ap(acc[mi][nt][1] + bs0);
                float o1 = tanh_ap(acc[mi][nt][2] + bt1) * sigm_ap(acc[mi][nt][3] + bs1);
                *(unsigned*)&OUT[col * OUTS + ch] =
                    (unsigned)f2bf(o0) | ((unsigned)f2bf(o1) << 16);
            }
        }
    }
    __syncthreads();

    // ---------- skip GEMM: M=240, K=128 -> fp32 RMW in d_out ----------
    {
        floatx4 acS[4][8];
#pragma unroll
        for (int mi = 0; mi < 4; mi++)
#pragma unroll
            for (int nt = 0; nt < 8; nt++) acS[mi][nt] = (floatx4){0.f, 0.f, 0.f, 0.f};
        for (int ks = 0; ks < 4; ks++) {
            short8 Bf[8];
#pragma unroll
            for (int nt = 0; nt < 8; nt++) {
                int col = nt * 16 + n;
                Bf[nt] = *(const short8*)&OUT[col * OUTS + ks * 32 + q * 8];
            }
#pragma unroll
            for (int mi = 0; mi < 4; mi++) {
                if (mi < mtn) {
                    short8 A = *(const short8*)(wp + ((size_t)(165 + (mtb + mi) * 4 + ks) * 64 + lane) * 8);
#pragma unroll
                    for (int nt = 0; nt < 8; nt++)
                        acS[mi][nt] = MFMA16(A, Bf[nt], acS[mi][nt], 0, 0, 0);
                }
            }
        }
#pragma unroll
        for (int mi = 0; mi < 4; mi++) {
            if (mi < mtn) {
                int mt = mtb + mi;
                int r0 = 16 * mt + 4 * q;
                floatx4 bb = *(const floatx4*)&BIAS[240 + r0];
#pragma unroll
                for (int nt = 0; nt < 8; nt++) {
                    int t = t0 + nt * 16 + n;
                    float* sp = skip + ((size_t)(b * NCLS) + r0) * TLEN + t;
#pragma unroll
                    for (int r = 0; r < 4; r++)
                        sp[(size_t)r * TLEN] += acS[mi][nt][r] + bb[r];
                }
            }
        }
    }

    // ---------- res GEMM: M=128(120), K=128, + residual ----------
    {
        floatx4 acR[2][8];
#pragma unroll
        for (int mi = 0; mi < 2; mi++)
#pragma unroll
            for (int nt = 0; nt < 8; nt++) acR[mi][nt] = (floatx4){0.f, 0.f, 0.f, 0.f};
        for (int ks = 0; ks < 4; ks++) {
            short8 Bf[8];
#pragma unroll
            for (int nt = 0; nt < 8; nt++) {
                int col = nt * 16 + n;
                Bf[nt] = *(const short8*)&OUT[col * OUTS + ks * 32 + q * 8];
            }
#pragma unroll
            for (int mi = 0; mi < 2; mi++) {
                short8 A = *(const short8*)(wp + ((size_t)(225 + (2 * w + mi) * 4 + ks) * 64 + lane) * 8);
#pragma unroll
                for (int nt = 0; nt < 8; nt++)
                    acR[mi][nt] = MFMA16(A, Bf[nt], acR[mi][nt], 0, 0, 0);
            }
        }
#pragma unroll
        for (int mi = 0; mi < 2; mi++) {
            int mt = 2 * w + mi;
            int r0 = 16 * mt + 4 * q;
            bool pad = (r0 >= RCH);        // rows 120..127: store zeros
            floatx4 bb = *(const floatx4*)&BIAS[480 + r0];
#pragma unroll
            for (int nt = 0; nt < 8; nt++) {
                int t = t0 + nt * 16 + n;
                const unsigned short* rip = resIn + (bT + t) * CP + r0;
                unsigned short* rop = resOut + (bT + t) * CP + r0;
                uint2 ri = *(const uint2*)rip;
                float v0 = acR[mi][nt][0] + bb[0] + bf2f((unsigned short)(ri.x & 0xffff));
                float v1 = acR[mi][nt][1] + bb[1] + bf2f((unsigned short)(ri.x >> 16));
                float v2 = acR[mi][nt][2] + bb[2] + bf2f((unsigned short)(ri.y & 0xffff));
                float v3 = acR[mi][nt][3] + bb[3] + bf2f((unsigned short)(ri.y >> 16));
                uint2 ov;
                ov.x = pad ? 0u : ((unsigned)f2bf(v0) | ((unsigned)f2bf(v1) << 16));
                ov.y = pad ? 0u : ((unsigned)f2bf(v2) | ((unsigned)f2bf(v3) << 16));
                *(uint2*)rop = ov;
            }
        }
    }
}

// ---- final: end = We @ relu(Wo @ relu(skip) + bo) + be  (MFMA) -------------
__global__ __launch_bounds__(256, 2) void k_final4(
    float* __restrict__ io,                    // fp32 [B][256][T]; in rows<240, out all
    const unsigned short* __restrict__ wpO,    // out_w frags (16mt x 8ks)
    const unsigned short* __restrict__ wpE,    // end_w frags
    const float* __restrict__ bpF) {           // out_b(256) | end_b(256)
    __shared__ __align__(16) unsigned short X[TSF * XES];
    __shared__ __align__(16) unsigned short E[TSF * XES];
    __shared__ float BF[512];

    const int tid = threadIdx.x;
    const int lane = tid & 63;
    const int n = lane & 15, q = lane >> 4;
    const int w = __builtin_amdgcn_readfirstlane(tid >> 6);
    const int t0 = blockIdx.x * TSF;
    const int b = blockIdx.y;

    for (int i = tid; i < 512; i += 256) BF[i] = bpF[i];
    for (int i = tid; i < SCH * TSF; i += 256) {
        int row = i >> 6, col = i & 63;
        float v = io[((size_t)(b * NCLS) + row) * TLEN + t0 + col];
        X[col * XES + row] = f2bf(fmaxf(v, 0.f));
    }
    for (int i = tid; i < (NCLS - SCH) * TSF; i += 256) {  // zero K-pad 240..255
        int row = SCH + (i >> 6), col = i & 63;
        X[col * XES + row] = 0;
    }
    __syncthreads();

    const int mtb = w * 4;
    // GEMM1: o = relu(Wo @ relu(skip) + bo), K=256
    {
        floatx4 acc[4][4];
#pragma unroll
        for (int mi = 0; mi < 4; mi++)
#pragma unroll
            for (int nt = 0; nt < 4; nt++) acc[mi][nt] = (floatx4){0.f, 0.f, 0.f, 0.f};
        for (int ks = 0; ks < 8; ks++) {
            short8 Bf[4];
#pragma unroll
            for (int nt = 0; nt < 4; nt++) {
                int col = nt * 16 + n;
                Bf[nt] = *(const short8*)&X[col * XES + ks * 32 + q * 8];
            }
#pragma unroll
            for (int mi = 0; mi < 4; mi++) {
                short8 A = *(const short8*)(wpO + ((size_t)((mtb + mi) * 8 + ks) * 64 + lane) * 8);
#pragma unroll
                for (int nt = 0; nt < 4; nt++)
                    acc[mi][nt] = MFMA16(A, Bf[nt], acc[mi][nt], 0, 0, 0);
            }
        }
#pragma unroll
        for (int mi = 0; mi < 4; mi++) {
            int ch0 = 16 * (mtb + mi) + 4 * q;
#pragma unroll
            for (int nt = 0; nt < 4; nt++) {
                int col = nt * 16 + n;
                float v0 = fmaxf(acc[mi][nt][0] + BF[ch0], 0.f);
                float v1 = fmaxf(acc[mi][nt][1] + BF[ch0 + 1], 0.f);
                float v2 = fmaxf(acc[mi][nt][2] + BF[ch0 + 2], 0.f);
                float v3 = fmaxf(acc[mi][nt][3] + BF[ch0 + 3], 0.f);
                *(unsigned*)&E[col * XES + ch0] = (unsigned)f2bf(v0) | ((unsigned)f2bf(v1) << 16);
                *(unsigned*)&E[col * XES + ch0 + 2] = (unsigned)f2bf(v2) | ((unsigned)f2bf(v3) << 16);
            }
        }
    }
    __syncthreads();
    // GEMM2: end = We @ o + be, K=256 -> fp32 out (in place, own tile)
    {
        floatx4 acc[4][4];
#pragma unroll
        for (int mi = 0; mi < 4; mi++)
#pragma unroll
            for (int nt = 0; nt < 4; nt++) acc[mi][nt] = (floatx4){0.f, 0.f, 0.f, 0.f};
        for (int ks = 0; ks < 8; ks++) {
            short8 Bf[4];
#pragma unroll
            for (int nt = 0; nt < 4; nt++) {
                int col = nt * 16 + n;
                Bf[nt] = *(const short8*)&E[col * XES + ks * 32 + q * 8];
            }
#pragma unroll
            for (int mi = 0; mi < 4; mi++) {
                short8 A = *(const short8*)(wpE + ((size_t)((mtb + mi) * 8 + ks) * 64 + lane) * 8);
#pragma unroll
                for (int nt = 0; nt < 4; nt++)
                    acc[mi][nt] = MFMA16(A, Bf[nt], acc[mi][nt], 0, 0, 0);
            }
        }
#pragma unroll
        for (int mi = 0; mi < 4; mi++) {
            int r0 = 16 * (mtb + mi) + 4 * q;
#pragma unroll
            for (int nt = 0; nt < 4; nt++) {
                int t = t0 + nt * 16 + n;
#pragma unroll
                for (int r = 0; r < 4; r++)
                    io[((size_t)(b * NCLS) + r0 + r) * TLEN + t] =
                        acc[mi][nt][r] + BF[256 + r0 + r];
            }
        }
    }
}

extern "C" void kernel_launch(void* const* d_in, const int* in_sizes, int n_in,
                              void* d_out, int out_size, void* d_ws, size_t ws_size,
                              hipStream_t stream) {
    (void)in_sizes; (void)n_in; (void)ws_size;
    const float* wav    = (const float*)d_in[0];
    const float* cond   = (const float*)d_in[1];
    const float* wav_w  = (const float*)d_in[2];
    const float* wav_b  = (const float*)d_in[3];
    const float* cond_w = (const float*)d_in[4];
    const float* cond_b = (const float*)d_in[5];
    const float* dil_w  = (const float*)d_in[6];
    const float* dil_b  = (const float*)d_in[7];
    const float* skip_w = (const float*)d_in[8];
    const float* skip_b = (const float*)d_in[9];
    const float* res_w  = (const float*)d_in[10];
    const float* res_b  = (const float*)d_in[11];
    const float* out_w  = (const float*)d_in[12];
    const float* out_b  = (const float*)d_in[13];
    const float* end_w  = (const float*)d_in[14];
    const float* end_b  = (const float*)d_in[15];

    // ws layout (bytes): resA 33.5M | resB 33.5M | condp 25.2M | wp 4.5M | bp 40K
    const size_t resElems = (size_t)BSZ * TLEN * CP;       // 16,777,216
    unsigned short* resA  = (unsigned short*)d_ws;
    unsigned short* resB  = resA + resElems;
    unsigned short* condp = resB + resElems;
    unsigned short* wp    = condp + (size_t)BSZ * TLEN * CC;
    float* bp             = (float*)(wp + (size_t)FR_TOT * 512);
    float* skip           = (float*)d_out;                 // fp32 [B][256][T]

    hipMemsetAsync(skip, 0, (size_t)out_size * sizeof(float), stream);
    k_packw<<<dim3((NWELEM + 255) / 256), 256, 0, stream>>>(
        dil_w, cond_w, skip_w, res_w, out_w, end_w, wp);
    k_packb<<<dim3((NBELEM + 255) / 256), 256, 0, stream>>>(
        dil_b, cond_b, skip_b, res_b, out_b, end_b, bp);
    k_init2<<<dim3(BSZ * TLEN / 256), 256, 0, stream>>>(wav, wav_w, wav_b, resA);
    k_packc<<<dim3(TLEN / 64, BSZ), 256, 0, stream>>>(cond, condp);

    unsigned short* rin = resA;
    unsigned short* rout = resB;
    for (int i = 0; i < NBLK; i++) {
        int d = 1 << (i & 7);
        k_block4<<<dim3(TLEN / TSB, BSZ), 256, 0, stream>>>(
            rin, rout, condp, skip,
            wp + (size_t)i * FR_BLK * 512,
            bp + (size_t)i * BIA_BLK,
            d);
        unsigned short* tmp = rin; rin = rout; rout = tmp;
    }
    k_final4<<<dim3(TLEN / TSF, BSZ), 256, 0, stream>>>(
        skip,
        wp + (size_t)(NBLK * FR_BLK) * 512,
        wp + (size_t)(NBLK * FR_BLK + 128) * 512,
        bp + NBLK * BIA_BLK);
}

// Round 5
// 1857.376 us; speedup vs baseline: 32.5331x; 1.1622x over previous
//
#include <hip/hip_runtime.h>
#include <hip/hip_fp16.h>

// WaveNet forward, MI355X — round 5: bf16 MFMA + fp16 skip accumulator.
// B=4, T=32768, NM=80, RC=120, SC=240, NB=16, ND=8, NC=256. fp32 I/O.
// Path A (ws_size >= 160 MB): skip accumulates fp16 in d_ws; k_final writes
// d_out directly (no aliasing, no d_out memset).
// Path B (fallback = round-4 proven): skip fp32 in d_out, in-place final.

#define BSZ  4
#define TLEN 32768
#define NMEL 80
#define RCH  120
#define SCH  240
#define NBLK 16
#define NCLS 256
#define CP   128   // res channel pad
#define CC   96    // cond channel pad
#define TSB  128   // t-cols per k_block wg
#define TSF  64    // t-cols per k_final wg
#define OUTS 136   // LDS col stride for out tile
#define XES  264   // LDS col stride in k_final

typedef __attribute__((ext_vector_type(8))) short short8;
typedef __attribute__((ext_vector_type(4))) float floatx4;
#define MFMA16 __builtin_amdgcn_mfma_f32_16x16x32_bf16

__device__ __forceinline__ float bf2f(unsigned short u) {
    return __uint_as_float(((unsigned)u) << 16);
}
__device__ __forceinline__ unsigned short f2bf(float f) {
    unsigned x = __float_as_uint(f);
    return (unsigned short)((x + 0x7fffu + ((x >> 16) & 1u)) >> 16);  // rne
}
__device__ __forceinline__ float h2f(unsigned short u) {
    return __half2float(__ushort_as_half(u));
}
__device__ __forceinline__ unsigned short f2h(float f) {
    return __half_as_ushort(__float2half(f));
}
__device__ __forceinline__ float tanh_ap(float x) {
    x = fminf(fmaxf(x, -18.f), 18.f);
    float e = __expf(2.f * x);
    return (e - 1.f) / (e + 1.f);
}
__device__ __forceinline__ float sigm_ap(float x) {
    x = fminf(fmaxf(x, -30.f), 30.f);
    return 1.f / (1.f + __expf(-x));
}

// ---- packed-weight geometry (unchanged from round 4) -----------------------
#define FR_BLK   257
#define FR_TOT   4368
#define NWELEM   (FR_TOT * 512)
#define BIA_BLK  608
#define NBELEM   (NBLK * BIA_BLK + 512)

__global__ void k_packw(const float* __restrict__ dil_w, const float* __restrict__ cond_w,
                        const float* __restrict__ skip_w, const float* __restrict__ res_w,
                        const float* __restrict__ out_w,  const float* __restrict__ end_w,
                        unsigned short* __restrict__ dst) {
    int idx = blockIdx.x * 256 + threadIdx.x;
    if (idx >= NWELEM) return;
    int fid = idx >> 9;
    int r   = idx & 511;
    int lane = r >> 3, j = r & 7;
    int m16 = lane & 15, q = lane >> 4;
    float v = 0.f;
    if (fid < NBLK * FR_BLK) {
        int blk = fid / FR_BLK, f = fid % FR_BLK;
        if (f < 165) {                      // gate: [240 interleaved][352]
            int mt = f / 11, ks = f % 11;
            int row = 16 * mt + m16;
            int kk  = ks * 32 + q * 8 + j;
            int c = row >> 1, br = row & 1;
            int srow = c + 120 * br;
            if (kk < 128) {
                if (kk < 120) v = dil_w[((size_t)(blk * 240 + srow) * 120 + kk) * 2 + 0];
            } else if (kk < 256) {
                int ch = kk - 128;
                if (ch < 120) v = dil_w[((size_t)(blk * 240 + srow) * 120 + ch) * 2 + 1];
            } else {
                int ch = kk - 256;
                if (ch < 80) v = cond_w[(size_t)(blk * 240 + srow) * 80 + ch];
            }
        } else if (f < 225) {               // skip: [240][128]
            int f2 = f - 165, mt = f2 / 4, ks = f2 % 4;
            int row = 16 * mt + m16;
            int kk = ks * 32 + q * 8 + j;
            if (kk < 120) v = skip_w[(size_t)(blk * 240 + row) * 120 + kk];
        } else {                            // res: [128][128]
            int f2 = f - 225, mt = f2 / 4, ks = f2 % 4;
            int row = 16 * mt + m16;
            int kk = ks * 32 + q * 8 + j;
            if (row < 120 && kk < 120) v = res_w[(size_t)(blk * 120 + row) * 120 + kk];
        }
    } else if (fid < NBLK * FR_BLK + 128) { // out_w
        int f = fid - NBLK * FR_BLK, mt = f / 8, ks = f % 8;
        int row = 16 * mt + m16;
        int kk = ks * 32 + q * 8 + j;
        if (kk < 240) v = out_w[(size_t)row * 240 + kk];
    } else {                                // end_w
        int f = fid - NBLK * FR_BLK - 128, mt = f / 8, ks = f % 8;
        int row = 16 * mt + m16;
        int kk = ks * 32 + q * 8 + j;
        v = end_w[(size_t)row * 256 + kk];
    }
    dst[idx] = f2bf(v);
}

__global__ void k_packb(const float* __restrict__ dil_b, const float* __restrict__ cond_b,
                        const float* __restrict__ skip_b, const float* __restrict__ res_b,
                        const float* __restrict__ out_b,  const float* __restrict__ end_b,
                        float* __restrict__ dst) {
    int idx = blockIdx.x * 256 + threadIdx.x;
    if (idx >= NBELEM) return;
    float v;
    if (idx < NBLK * BIA_BLK) {
        int blk = idx / BIA_BLK, f = idx % BIA_BLK;
        if (f < 240) {
            int c = f >> 1, br = f & 1;
            int srow = c + 120 * br;
            v = dil_b[blk * 240 + srow] + cond_b[blk * 240 + srow];
        } else if (f < 480) {
            v = skip_b[blk * 240 + (f - 240)];
        } else {
            int rr = f - 480;
            v = rr < 120 ? res_b[blk * 120 + rr] : 0.f;
        }
    } else {
        int f = idx - NBLK * BIA_BLK;
        v = f < 256 ? out_b[f] : end_b[f - 256];
    }
    dst[idx] = v;
}

__global__ void k_init2(const float* __restrict__ wav, const float* __restrict__ wav_w,
                        const float* __restrict__ wav_b, unsigned short* __restrict__ res) {
    int idx = blockIdx.x * 256 + threadIdx.x;
    float wv = wav[idx];
    unsigned* dst = (unsigned*)(res + (size_t)idx * CP);
#pragma unroll
    for (int c = 0; c < RCH; c += 2) {
        float v0 = wav_w[c] * wv + wav_b[c];
        float v1 = wav_w[c + 1] * wv + wav_b[c + 1];
        dst[c >> 1] = (unsigned)f2bf(v0) | ((unsigned)f2bf(v1) << 16);
    }
#pragma unroll
    for (int c = RCH; c < CP; c += 2) dst[c >> 1] = 0u;
}

__global__ __launch_bounds__(256) void k_packc(const float* __restrict__ cond,
                                               unsigned short* __restrict__ dst) {
    __shared__ unsigned short CT[64 * CC];
    const int tid = threadIdx.x;
    const int t0 = blockIdx.x * 64;
    const int b = blockIdx.y;
    for (int i = tid; i < NMEL * 64; i += 256) {
        int c = i >> 6, tt = i & 63;
        CT[tt * CC + c] = f2bf(cond[((size_t)b * NMEL + c) * TLEN + t0 + tt]);
    }
    for (int i = tid; i < (CC - NMEL) * 64; i += 256) {
        int c = NMEL + (i >> 6), tt = i & 63;
        CT[tt * CC + c] = 0;
    }
    __syncthreads();
    unsigned* dp = (unsigned*)(dst + ((size_t)b * TLEN + t0) * CC);
    const unsigned* sp = (const unsigned*)CT;
    for (int i = tid; i < 64 * (CC / 2); i += 256) dp[i] = sp[i];
}

// ---- residual block (MFMA). HF=true: fp16 skip in ws [B][240][T].
//      HF=false: fp32 skip in d_out [B][256][T] rows 0..239. -----------------
template <bool HF>
__global__ __launch_bounds__(256, 2) void k_block4(
    const unsigned short* __restrict__ resIn,
    unsigned short* __restrict__ resOut,
    const unsigned short* __restrict__ condp,
    void* __restrict__ skipPtr,
    const unsigned short* __restrict__ wp,
    const float* __restrict__ bp,
    int d) {
    __shared__ __align__(16) unsigned short OUT[TSB * OUTS];
    __shared__ __align__(16) float BIAS[BIA_BLK];

    const int tid = threadIdx.x;
    const int lane = tid & 63;
    const int n = lane & 15, q = lane >> 4;
    const int w = __builtin_amdgcn_readfirstlane(tid >> 6);
    const int t0 = blockIdx.x * TSB;
    const int b = blockIdx.y;
    const size_t bT = (size_t)b * TLEN;

    for (int i = tid; i < BIA_BLK; i += 256) BIAS[i] = bp[i];
    for (int i = tid; i < TSB * 8; i += 256) {
        int col = i >> 3, ch = RCH + (i & 7);
        OUT[col * OUTS + ch] = 0;
    }

    const int mtb = w * 4;
    const int mtn = (w == 3) ? 3 : 4;
    const unsigned short* resb = resIn + bT * CP;
    const unsigned short* conb = condp + bT * CC;

    // ---------- gate GEMM: M=240(interleaved), K=352 ----------
    floatx4 acc[4][8];
#pragma unroll
    for (int mi = 0; mi < 4; mi++)
#pragma unroll
        for (int nt = 0; nt < 8; nt++) acc[mi][nt] = (floatx4){0.f, 0.f, 0.f, 0.f};

    for (int ks = 0; ks < 11; ks++) {
        short8 Bf[8];
        if (ks < 8) {
            const int dd = (ks < 4) ? d : 0;
            const int kl = (ks & 3) * 32 + q * 8;
            if (t0 >= TSB || dd == 0) {
#pragma unroll
                for (int nt = 0; nt < 8; nt++) {
                    int t = t0 + nt * 16 + n - dd;
                    Bf[nt] = *(const short8*)(resb + (size_t)t * CP + kl);
                }
            } else {
#pragma unroll
                for (int nt = 0; nt < 8; nt++) {
                    int t = t0 + nt * 16 + n - dd;
                    int tc = t < 0 ? 0 : t;
                    short8 v = *(const short8*)(resb + (size_t)tc * CP + kl);
                    if (t < 0) v = (short8){0, 0, 0, 0, 0, 0, 0, 0};
                    Bf[nt] = v;
                }
            }
        } else {
            const int kl = (ks - 8) * 32 + q * 8;
#pragma unroll
            for (int nt = 0; nt < 8; nt++) {
                int t = t0 + nt * 16 + n;
                Bf[nt] = *(const short8*)(conb + (size_t)t * CC + kl);
            }
        }
#pragma unroll
        for (int mi = 0; mi < 4; mi++) {
            if (mi < mtn) {
                short8 A = *(const short8*)(wp + ((size_t)((mtb + mi) * 11 + ks) * 64 + lane) * 8);
#pragma unroll
                for (int nt = 0; nt < 8; nt++)
                    acc[mi][nt] = MFMA16(A, Bf[nt], acc[mi][nt], 0, 0, 0);
            }
        }
    }

    // gating epilogue -> OUT
#pragma unroll
    for (int mi = 0; mi < 4; mi++) {
        if (mi < mtn) {
            int mt = mtb + mi;
            int p0 = 16 * mt + 4 * q;
            int ch = 8 * mt + 2 * q;
            float bt0 = BIAS[p0], bs0 = BIAS[p0 + 1];
            float bt1 = BIAS[p0 + 2], bs1 = BIAS[p0 + 3];
#pragma unroll
            for (int nt = 0; nt < 8; nt++) {
                int col = nt * 16 + n;
                float o0 = tanh_ap(acc[mi][nt][0] + bt0) * sigm_ap(acc[mi][nt][1] + bs0);
                float o1 = tanh_ap(acc[mi][nt][2] + bt1) * sigm_ap(acc[mi][nt][3] + bs1);
                *(unsigned*)&OUT[col * OUTS + ch] =
                    (unsigned)f2bf(o0) | ((unsigned)f2bf(o1) << 16);
            }
        }
    }
    __syncthreads();

    // ---------- skip GEMM: M=240, K=128 ----------
    {
        floatx4 acS[4][8];
#pragma unroll
        for (int mi = 0; mi < 4; mi++)
#pragma unroll
            for (int nt = 0; nt < 8; nt++) acS[mi][nt] = (floatx4){0.f, 0.f, 0.f, 0.f};
        for (int ks = 0; ks < 4; ks++) {
            short8 Bf[8];
#pragma unroll
            for (int nt = 0; nt < 8; nt++) {
                int col = nt * 16 + n;
                Bf[nt] = *(const short8*)&OUT[col * OUTS + ks * 32 + q * 8];
            }
#pragma unroll
            for (int mi = 0; mi < 4; mi++) {
                if (mi < mtn) {
                    short8 A = *(const short8*)(wp + ((size_t)(165 + (mtb + mi) * 4 + ks) * 64 + lane) * 8);
#pragma unroll
                    for (int nt = 0; nt < 8; nt++)
                        acS[mi][nt] = MFMA16(A, Bf[nt], acS[mi][nt], 0, 0, 0);
                }
            }
        }
#pragma unroll
        for (int mi = 0; mi < 4; mi++) {
            if (mi < mtn) {
                int mt = mtb + mi;
                int r0 = 16 * mt + 4 * q;
                floatx4 bb = *(const floatx4*)&BIAS[240 + r0];
#pragma unroll
                for (int nt = 0; nt < 8; nt++) {
                    int t = t0 + nt * 16 + n;
                    if (HF) {
                        unsigned short* sp = (unsigned short*)skipPtr +
                            ((size_t)(b * SCH) + r0) * TLEN + t;
#pragma unroll
                        for (int r = 0; r < 4; r++) {
                            size_t off = (size_t)r * TLEN;
                            sp[off] = f2h(h2f(sp[off]) + acS[mi][nt][r] + bb[r]);
                        }
                    } else {
                        float* sp = (float*)skipPtr + ((size_t)(b * NCLS) + r0) * TLEN + t;
#pragma unroll
                        for (int r = 0; r < 4; r++)
                            sp[(size_t)r * TLEN] += acS[mi][nt][r] + bb[r];
                    }
                }
            }
        }
    }

    // ---------- res GEMM: M=128(120), K=128, + residual ----------
    {
        floatx4 acR[2][8];
#pragma unroll
        for (int mi = 0; mi < 2; mi++)
#pragma unroll
            for (int nt = 0; nt < 8; nt++) acR[mi][nt] = (floatx4){0.f, 0.f, 0.f, 0.f};
        for (int ks = 0; ks < 4; ks++) {
            short8 Bf[8];
#pragma unroll
            for (int nt = 0; nt < 8; nt++) {
                int col = nt * 16 + n;
                Bf[nt] = *(const short8*)&OUT[col * OUTS + ks * 32 + q * 8];
            }
#pragma unroll
            for (int mi = 0; mi < 2; mi++) {
                short8 A = *(const short8*)(wp + ((size_t)(225 + (2 * w + mi) * 4 + ks) * 64 + lane) * 8);
#pragma unroll
                for (int nt = 0; nt < 8; nt++)
                    acR[mi][nt] = MFMA16(A, Bf[nt], acR[mi][nt], 0, 0, 0);
            }
        }
#pragma unroll
        for (int mi = 0; mi < 2; mi++) {
            int mt = 2 * w + mi;
            int r0 = 16 * mt + 4 * q;
            bool pad = (r0 >= RCH);
            floatx4 bb = *(const floatx4*)&BIAS[480 + r0];
#pragma unroll
            for (int nt = 0; nt < 8; nt++) {
                int t = t0 + nt * 16 + n;
                const unsigned short* rip = resIn + (bT + t) * CP + r0;
                unsigned short* rop = resOut + (bT + t) * CP + r0;
                uint2 ri = *(const uint2*)rip;
                float v0 = acR[mi][nt][0] + bb[0] + bf2f((unsigned short)(ri.x & 0xffff));
                float v1 = acR[mi][nt][1] + bb[1] + bf2f((unsigned short)(ri.x >> 16));
                float v2 = acR[mi][nt][2] + bb[2] + bf2f((unsigned short)(ri.y & 0xffff));
                float v3 = acR[mi][nt][3] + bb[3] + bf2f((unsigned short)(ri.y >> 16));
                uint2 ov;
                ov.x = pad ? 0u : ((unsigned)f2bf(v0) | ((unsigned)f2bf(v1) << 16));
                ov.y = pad ? 0u : ((unsigned)f2bf(v2) | ((unsigned)f2bf(v3) << 16));
                *(uint2*)rop = ov;
            }
        }
    }
}

// ---- final. HF=true: read fp16 skip from ws, write fp32 d_out (no alias).
//      HF=false: in-place fp32 in d_out (round-4 scheme). ----------------
template <bool HF>
__global__ __launch_bounds__(256, 2) void k_final4(
    const void* __restrict__ skipPtr,
    float* __restrict__ io,
    const unsigned short* __restrict__ wpO,
    const unsigned short* __restrict__ wpE,
    const float* __restrict__ bpF) {
    __shared__ __align__(16) unsigned short X[TSF * XES];
    __shared__ __align__(16) unsigned short E[TSF * XES];
    __shared__ float BF[512];

    const int tid = threadIdx.x;
    const int lane = tid & 63;
    const int n = lane & 15, q = lane >> 4;
    const int w = __builtin_amdgcn_readfirstlane(tid >> 6);
    const int t0 = blockIdx.x * TSF;
    const int b = blockIdx.y;

    for (int i = tid; i < 512; i += 256) BF[i] = bpF[i];
    for (int i = tid; i < SCH * TSF; i += 256) {
        int row = i >> 6, col = i & 63;
        float v;
        if (HF) v = h2f(((const unsigned short*)skipPtr)[((size_t)(b * SCH) + row) * TLEN + t0 + col]);
        else    v = io[((size_t)(b * NCLS) + row) * TLEN + t0 + col];
        X[col * XES + row] = f2bf(fmaxf(v, 0.f));
    }
    for (int i = tid; i < (NCLS - SCH) * TSF; i += 256) {
        int row = SCH + (i >> 6), col = i & 63;
        X[col * XES + row] = 0;
    }
    __syncthreads();

    const int mtb = w * 4;
    {
        floatx4 acc[4][4];
#pragma unroll
        for (int mi = 0; mi < 4; mi++)
#pragma unroll
            for (int nt = 0; nt < 4; nt++) acc[mi][nt] = (floatx4){0.f, 0.f, 0.f, 0.f};
        for (int ks = 0; ks < 8; ks++) {
            short8 Bf[4];
#pragma unroll
            for (int nt = 0; nt < 4; nt++) {
                int col = nt * 16 + n;
                Bf[nt] = *(const short8*)&X[col * XES + ks * 32 + q * 8];
            }
#pragma unroll
            for (int mi = 0; mi < 4; mi++) {
                short8 A = *(const short8*)(wpO + ((size_t)((mtb + mi) * 8 + ks) * 64 + lane) * 8);
#pragma unroll
                for (int nt = 0; nt < 4; nt++)
                    acc[mi][nt] = MFMA16(A, Bf[nt], acc[mi][nt], 0, 0, 0);
            }
        }
#pragma unroll
        for (int mi = 0; mi < 4; mi++) {
            int ch0 = 16 * (mtb + mi) + 4 * q;
#pragma unroll
            for (int nt = 0; nt < 4; nt++) {
                int col = nt * 16 + n;
                float v0 = fmaxf(acc[mi][nt][0] + BF[ch0], 0.f);
                float v1 = fmaxf(acc[mi][nt][1] + BF[ch0 + 1], 0.f);
                float v2 = fmaxf(acc[mi][nt][2] + BF[ch0 + 2], 0.f);
                float v3 = fmaxf(acc[mi][nt][3] + BF[ch0 + 3], 0.f);
                *(unsigned*)&E[col * XES + ch0] = (unsigned)f2bf(v0) | ((unsigned)f2bf(v1) << 16);
                *(unsigned*)&E[col * XES + ch0 + 2] = (unsigned)f2bf(v2) | ((unsigned)f2bf(v3) << 16);
            }
        }
    }
    __syncthreads();
    {
        floatx4 acc[4][4];
#pragma unroll
        for (int mi = 0; mi < 4; mi++)
#pragma unroll
            for (int nt = 0; nt < 4; nt++) acc[mi][nt] = (floatx4){0.f, 0.f, 0.f, 0.f};
        for (int ks = 0; ks < 8; ks++) {
            short8 Bf[4];
#pragma unroll
            for (int nt = 0; nt < 4; nt++) {
                int col = nt * 16 + n;
                Bf[nt] = *(const short8*)&E[col * XES + ks * 32 + q * 8];
            }
#pragma unroll
            for (int mi = 0; mi < 4; mi++) {
                short8 A = *(const short8*)(wpE + ((size_t)((mtb + mi) * 8 + ks) * 64 + lane) * 8);
#pragma unroll
                for (int nt = 0; nt < 4; nt++)
                    acc[mi][nt] = MFMA16(A, Bf[nt], acc[mi][nt], 0, 0, 0);
            }
        }
#pragma unroll
        for (int mi = 0; mi < 4; mi++) {
            int r0 = 16 * (mtb + mi) + 4 * q;
#pragma unroll
            for (int nt = 0; nt < 4; nt++) {
                int t = t0 + nt * 16 + n;
#pragma unroll
                for (int r = 0; r < 4; r++)
                    io[((size_t)(b * NCLS) + r0 + r) * TLEN + t] =
                        acc[mi][nt][r] + BF[256 + r0 + r];
            }
        }
    }
}

extern "C" void kernel_launch(void* const* d_in, const int* in_sizes, int n_in,
                              void* d_out, int out_size, void* d_ws, size_t ws_size,
                              hipStream_t stream) {
    (void)in_sizes; (void)n_in;
    const float* wav    = (const float*)d_in[0];
    const float* cond   = (const float*)d_in[1];
    const float* wav_w  = (const float*)d_in[2];
    const float* wav_b  = (const float*)d_in[3];
    const float* cond_w = (const float*)d_in[4];
    const float* cond_b = (const float*)d_in[5];
    const float* dil_w  = (const float*)d_in[6];
    const float* dil_b  = (const float*)d_in[7];
    const float* skip_w = (const float*)d_in[8];
    const float* skip_b = (const float*)d_in[9];
    const float* res_w  = (const float*)d_in[10];
    const float* res_b  = (const float*)d_in[11];
    const float* out_w  = (const float*)d_in[12];
    const float* out_b  = (const float*)d_in[13];
    const float* end_w  = (const float*)d_in[14];
    const float* end_b  = (const float*)d_in[15];

    const size_t resElems = (size_t)BSZ * TLEN * CP;       // 16,777,216
    unsigned short* resA  = (unsigned short*)d_ws;
    unsigned short* resB  = resA + resElems;
    unsigned short* condp = resB + resElems;
    unsigned short* wp    = condp + (size_t)BSZ * TLEN * CC;
    float* bp             = (float*)(wp + (size_t)FR_TOT * 512);
    unsigned short* skipH = (unsigned short*)(bp + NBELEM);
    const size_t skipHBytes = (size_t)BSZ * SCH * TLEN * 2;  // 62,914,560
    const size_t needA = (size_t)((char*)(skipH) - (char*)d_ws) + skipHBytes;  // ~160 MB
    const bool hf = ws_size >= needA;

    void* skipPtr = hf ? (void*)skipH : (void*)d_out;
    if (hf) hipMemsetAsync(skipH, 0, skipHBytes, stream);
    else    hipMemsetAsync(d_out, 0, (size_t)out_size * sizeof(float), stream);

    k_packw<<<dim3((NWELEM + 255) / 256), 256, 0, stream>>>(
        dil_w, cond_w, skip_w, res_w, out_w, end_w, wp);
    k_packb<<<dim3((NBELEM + 255) / 256), 256, 0, stream>>>(
        dil_b, cond_b, skip_b, res_b, out_b, end_b, bp);
    k_init2<<<dim3(BSZ * TLEN / 256), 256, 0, stream>>>(wav, wav_w, wav_b, resA);
    k_packc<<<dim3(TLEN / 64, BSZ), 256, 0, stream>>>(cond, condp);

    unsigned short* rin = resA;
    unsigned short* rout = resB;
    for (int i = 0; i < NBLK; i++) {
        int d = 1 << (i & 7);
        if (hf)
            k_block4<true><<<dim3(TLEN / TSB, BSZ), 256, 0, stream>>>(
                rin, rout, condp, skipPtr,
                wp + (size_t)i * FR_BLK * 512, bp + (size_t)i * BIA_BLK, d);
        else
            k_block4<false><<<dim3(TLEN / TSB, BSZ), 256, 0, stream>>>(
                rin, rout, condp, skipPtr,
                wp + (size_t)i * FR_BLK * 512, bp + (size_t)i * BIA_BLK, d);
        unsigned short* tmp = rin; rin = rout; rout = tmp;
    }
    if (hf)
        k_final4<true><<<dim3(TLEN / TSF, BSZ), 256, 0, stream>>>(
            skipPtr, (float*)d_out,
            wp + (size_t)(NBLK * FR_BLK) * 512,
            wp + (size_t)(NBLK * FR_BLK + 128) * 512,
            bp + NBLK * BIA_BLK);
    else
        k_final4<false><<<dim3(TLEN / TSF, BSZ), 256, 0, stream>>>(
            skipPtr, (float*)d_out,
            wp + (size_t)(NBLK * FR_BLK) * 512,
            wp + (size_t)(NBLK * FR_BLK + 128) * 512,
            bp + NBLK * BIA_BLK);
}